// Round 1
// baseline (139.138 us; speedup 1.0000x reference)
//
#include <hip/hip_runtime.h>
#include <hip/hip_bf16.h>

typedef __attribute__((ext_vector_type(8))) short bf16x8;
typedef __attribute__((ext_vector_type(4))) float f32x4;

#define B_ROWS 4096
#define H_DIM  1024
#define TEMP_INV 20.0f
#define BLK 128
#define BK  32

__device__ __forceinline__ void gload_lds16(const void* g, void* l) {
  __builtin_amdgcn_global_load_lds(
      (const __attribute__((address_space(1))) void*)g,
      (__attribute__((address_space(3))) void*)l, 16, 0, 0);
}

// Kernel 1: row-normalize (f32, matching F.cosine_similarity eps) and cast to bf16.
// Blocks 0..15 also zero the rowsum accumulator (4096 floats).
__global__ __launch_bounds__(256) void normalize_kernel(
    const float* __restrict__ cls, const float* __restrict__ hid,
    __hip_bfloat16* __restrict__ Abf, __hip_bfloat16* __restrict__ Bbf,
    float* __restrict__ rowsum)
{
  int bid = blockIdx.x, tid = threadIdx.x;
  if (bid < 16) rowsum[bid * 256 + tid] = 0.0f;
  int row = bid & (B_ROWS - 1);
  const float* src = (bid < B_ROWS) ? cls : hid;
  __hip_bfloat16* dst = (bid < B_ROWS) ? Abf : Bbf;

  float4 v = reinterpret_cast<const float4*>(src + (size_t)row * H_DIM)[tid];
  float ss = v.x * v.x + v.y * v.y + v.z * v.z + v.w * v.w;
  #pragma unroll
  for (int off = 1; off < 64; off <<= 1) ss += __shfl_xor(ss, off, 64);
  __shared__ float wsum[4];
  if ((tid & 63) == 0) wsum[tid >> 6] = ss;
  __syncthreads();
  float total = wsum[0] + wsum[1] + wsum[2] + wsum[3];
  float scale = 1.0f / fmaxf(sqrtf(total), 1e-8f);

  union { ushort4 u; __hip_bfloat16 h[4]; } o;
  o.h[0] = __float2bfloat16(v.x * scale);
  o.h[1] = __float2bfloat16(v.y * scale);
  o.h[2] = __float2bfloat16(v.z * scale);
  o.h[3] = __float2bfloat16(v.w * scale);
  reinterpret_cast<ushort4*>(dst + (size_t)row * H_DIM)[tid] = o.u;
}

// Kernel 2: 128x128 tile NT-GEMM (sim = A_norm * B_norm^T / TEMP), fused
// exp + per-row partial-sum atomicAdd, diag capture on diagonal blocks.
__global__ __launch_bounds__(256) void gemm_kernel(
    const __hip_bfloat16* __restrict__ A, const __hip_bfloat16* __restrict__ Bm,
    float* __restrict__ rowsum, float* __restrict__ diag)
{
  __shared__ __hip_bfloat16 As[BLK * BK];
  __shared__ __hip_bfloat16 Bs[BLK * BK];

  int tid = threadIdx.x;
  int w = tid >> 6, lane = tid & 63;
  int bm = blockIdx.y, bn = blockIdx.x;
  int row0 = bm * BLK, col0 = bn * BLK;
  int wm = w & 1, wn = w >> 1;   // wave covers rows wm*64.., cols wn*64..

  f32x4 acc[4][4] = {};

  int srow = lane >> 2;          // 0..15 within 16-row chunk
  int scol = (lane & 3) * 8;     // element offset 0/8/16/24
  int fr   = lane & 15;
  int koff = (lane >> 4) * 8;

  for (int kt = 0; kt < H_DIM; kt += BK) {
    #pragma unroll
    for (int i = 0; i < 2; i++) {
      int chunk = i * 4 + w;     // 0..7 -> rows chunk*16..+15
      const __hip_bfloat16* ga =
          A + (size_t)(row0 + chunk * 16 + srow) * H_DIM + kt + scol;
      gload_lds16(ga, As + chunk * 512);
      const __hip_bfloat16* gb =
          Bm + (size_t)(col0 + chunk * 16 + srow) * H_DIM + kt + scol;
      gload_lds16(gb, Bs + chunk * 512);
    }
    __syncthreads();

    bf16x8 af[4], bfr[4];
    #pragma unroll
    for (int m = 0; m < 4; m++)
      af[m] = *(const bf16x8*)&As[(wm * 64 + m * 16 + fr) * BK + koff];
    #pragma unroll
    for (int n = 0; n < 4; n++)
      bfr[n] = *(const bf16x8*)&Bs[(wn * 64 + n * 16 + fr) * BK + koff];

    #pragma unroll
    for (int m = 0; m < 4; m++)
      #pragma unroll
      for (int n = 0; n < 4; n++)
        acc[m][n] = __builtin_amdgcn_mfma_f32_16x16x32_bf16(af[m], bfr[n], acc[m][n], 0, 0, 0);

    __syncthreads();
  }

  // Epilogue: sim = acc * 20; capture diag; p = exp(sim); per-row reduce.
  bool isdiag = (bm == bn);
  int g = lane >> 4;             // C/D layout: row=(lane>>4)*4+r, col=lane&15
  #pragma unroll
  for (int m = 0; m < 4; m++) {
    int rowb = row0 + wm * 64 + m * 16 + g * 4;
    float p[4] = {0.f, 0.f, 0.f, 0.f};
    #pragma unroll
    for (int n = 0; n < 4; n++) {
      int colb = col0 + wn * 64 + n * 16 + (lane & 15);
      #pragma unroll
      for (int r = 0; r < 4; r++) {
        float sim = acc[m][n][r] * TEMP_INV;
        if (isdiag && (rowb + r == colb)) diag[rowb + r] = sim;
        p[r] += __expf(sim);
      }
    }
    #pragma unroll
    for (int r = 0; r < 4; r++) {
      float s = p[r];
      s += __shfl_xor(s, 1, 64);
      s += __shfl_xor(s, 2, 64);
      s += __shfl_xor(s, 4, 64);
      s += __shfl_xor(s, 8, 64);
      if ((lane & 15) == 0) atomicAdd(&rowsum[rowb + r], s);
    }
  }
}

// Kernel 3: out = mean(log(rowsum) - diag)
__global__ __launch_bounds__(1024) void finalize_kernel(
    const float* __restrict__ rowsum, const float* __restrict__ diag,
    float* __restrict__ out)
{
  int tid = threadIdx.x;
  float acc = 0.f;
  for (int i = tid; i < B_ROWS; i += 1024)
    acc += logf(rowsum[i]) - diag[i];
  #pragma unroll
  for (int off = 1; off < 64; off <<= 1) acc += __shfl_xor(acc, off, 64);
  __shared__ float wsum[16];
  if ((tid & 63) == 0) wsum[tid >> 6] = acc;
  __syncthreads();
  if (tid == 0) {
    float t = 0.f;
    #pragma unroll
    for (int i = 0; i < 16; i++) t += wsum[i];
    out[0] = t * (1.0f / B_ROWS);
  }
}

extern "C" void kernel_launch(void* const* d_in, const int* in_sizes, int n_in,
                              void* d_out, int out_size, void* d_ws, size_t ws_size,
                              hipStream_t stream)
{
  const float* cls = (const float*)d_in[0];
  const float* hid = (const float*)d_in[1];
  float* out = (float*)d_out;
  char* ws = (char*)d_ws;

  __hip_bfloat16* Abf = (__hip_bfloat16*)ws;                               // 8 MB
  __hip_bfloat16* Bbf = (__hip_bfloat16*)(ws + (size_t)B_ROWS * H_DIM * 2); // 8 MB
  float* rowsum = (float*)(ws + (size_t)B_ROWS * H_DIM * 4);               // 16 KB
  float* diag   = rowsum + B_ROWS;                                          // 16 KB

  hipLaunchKernelGGL(normalize_kernel, dim3(2 * B_ROWS), dim3(256), 0, stream,
                     cls, hid, Abf, Bbf, rowsum);
  hipLaunchKernelGGL(gemm_kernel, dim3(B_ROWS / BLK, B_ROWS / BLK), dim3(256), 0, stream,
                     Abf, Bbf, rowsum, diag);
  hipLaunchKernelGGL(finalize_kernel, dim3(1), dim3(1024), 0, stream,
                     rowsum, diag, out);
}

// Round 2
// 117.930 us; speedup vs baseline: 1.1798x; 1.1798x over previous
//
#include <hip/hip_runtime.h>
#include <hip/hip_bf16.h>

typedef __attribute__((ext_vector_type(8))) short bf16x8;
typedef __attribute__((ext_vector_type(4))) float f32x4;

#define B_ROWS 4096
#define H_DIM  1024
#define TEMP_INV 20.0f
#define BM 256
#define BK 64
#define NT (H_DIM / BK)   // 16 K-tiles

__device__ __forceinline__ void gload_lds16(const void* g, void* l) {
  __builtin_amdgcn_global_load_lds(
      (const __attribute__((address_space(1))) void*)g,
      (__attribute__((address_space(3))) void*)l, 16, 0, 0);
}

// Kernel 1: row-normalize (f32, cosine_similarity eps) and cast to bf16.
// Blocks 0..15 also zero the rowsum accumulator.
__global__ __launch_bounds__(256) void normalize_kernel(
    const float* __restrict__ cls, const float* __restrict__ hid,
    __hip_bfloat16* __restrict__ Abf, __hip_bfloat16* __restrict__ Bbf,
    float* __restrict__ rowsum)
{
  int bid = blockIdx.x, tid = threadIdx.x;
  if (bid < 16) rowsum[bid * 256 + tid] = 0.0f;
  int row = bid & (B_ROWS - 1);
  const float* src = (bid < B_ROWS) ? cls : hid;
  __hip_bfloat16* dst = (bid < B_ROWS) ? Abf : Bbf;

  float4 v = reinterpret_cast<const float4*>(src + (size_t)row * H_DIM)[tid];
  float ss = v.x * v.x + v.y * v.y + v.z * v.z + v.w * v.w;
  #pragma unroll
  for (int off = 1; off < 64; off <<= 1) ss += __shfl_xor(ss, off, 64);
  __shared__ float wsum[4];
  if ((tid & 63) == 0) wsum[tid >> 6] = ss;
  __syncthreads();
  float total = wsum[0] + wsum[1] + wsum[2] + wsum[3];
  float scale = 1.0f / fmaxf(sqrtf(total), 1e-8f);

  union { ushort4 u; __hip_bfloat16 h[4]; } o;
  o.h[0] = __float2bfloat16(v.x * scale);
  o.h[1] = __float2bfloat16(v.y * scale);
  o.h[2] = __float2bfloat16(v.z * scale);
  o.h[3] = __float2bfloat16(v.w * scale);
  reinterpret_cast<ushort4*>(dst + (size_t)row * H_DIM)[tid] = o.u;
}

// Kernel 2: 256x256-tile NT-GEMM, 8 waves (2Mx4N), BK=64, double-buffered
// 128 KiB LDS, 4-phase schedule with counted vmcnt, XOR-swizzled LDS
// (linear gload_lds dest + inverse-swizzled global source + swizzled read).
// Fused exp + per-row partial-sum atomicAdd + diag capture.

#define LDS_RD_A(BUF, MB)                                                     \
  { _Pragma("unroll") for (int mi = 0; mi < 4; mi++) {                        \
      _Pragma("unroll") for (int ks = 0; ks < 2; ks++) {                      \
        af[mi][ks] = *(const bf16x8*)(&As[BUF][(rA2 ^ (ks << 6)) + ((MB) + mi) * 2048]); } } }

#define LDS_RD_B(BUF, NB)                                                     \
  { _Pragma("unroll") for (int ni = 0; ni < 2; ni++) {                        \
      _Pragma("unroll") for (int ks = 0; ks < 2; ks++) {                      \
        bfr[(NB) + ni][ks] = *(const bf16x8*)(&Bs[BUF][(rB2 ^ (ks << 6)) + ((NB) + ni) * 2048]); } } }

#define MFMA16(MB, NB)                                                        \
  { __builtin_amdgcn_s_setprio(1);                                            \
    _Pragma("unroll") for (int mi = 0; mi < 4; mi++) {                        \
      _Pragma("unroll") for (int ni = 0; ni < 2; ni++) {                      \
        _Pragma("unroll") for (int ks = 0; ks < 2; ks++) {                    \
          acc[(MB) + mi][(NB) + ni] = __builtin_amdgcn_mfma_f32_16x16x32_bf16(\
              af[mi][ks], bfr[(NB) + ni][ks], acc[(MB) + mi][(NB) + ni], 0, 0, 0); } } } \
    __builtin_amdgcn_s_setprio(0); }

#define BAR() { __builtin_amdgcn_s_barrier(); __builtin_amdgcn_sched_barrier(0); }

#define STAGE_A(BUF, TT, C)                                                   \
  gload_lds16(Abase + (size_t)(row0 + (C) * 64 + srow) * 2048 + (TT) * 128 + scolb, \
              &As[BUF][(C) * 8192 + tid * 16])
#define STAGE_B(BUF, TT, C)                                                   \
  gload_lds16(Bbase + (size_t)(col0 + (C) * 64 + srow) * 2048 + (TT) * 128 + scolb, \
              &Bs[BUF][(C) * 8192 + tid * 16])

// One K-tile: 4 phases + boundary. Stages during tile T fill tile T+1 in
// buf^1 (phases 1-3) and tile T+2's first chunk-pair in buf (boundary, after
// all reads of buf are barrier-complete). vmcnt(2) keeps 2 loads in flight.
#define KTILE(BUF, T_)                                                        \
  { const int Tn = (T_) + 1;                                                  \
    LDS_RD_A(BUF, 0); LDS_RD_B(BUF, 0);                                       \
    MFMA16(0, 0); BAR();                                                      \
    if (Tn < NT) { STAGE_A(BUF ^ 1, Tn, 2); STAGE_A(BUF ^ 1, Tn, 3); }        \
    LDS_RD_B(BUF, 2);                                                         \
    MFMA16(0, 2); BAR();                                                      \
    if (Tn < NT) { STAGE_B(BUF ^ 1, Tn, 0); STAGE_B(BUF ^ 1, Tn, 1); }        \
    LDS_RD_A(BUF, 4);                                                         \
    MFMA16(4, 0); BAR();                                                      \
    if (Tn < NT) { STAGE_B(BUF ^ 1, Tn, 2); STAGE_B(BUF ^ 1, Tn, 3); }        \
    MFMA16(4, 2);                                                             \
    if ((T_) + 2 < NT) {                                                      \
      STAGE_A(BUF, (T_) + 2, 0); STAGE_A(BUF, (T_) + 2, 1);                   \
      asm volatile("s_waitcnt vmcnt(2)" ::: "memory");                        \
      BAR();                                                                  \
    } else if (Tn < NT) {                                                     \
      asm volatile("s_waitcnt vmcnt(0)" ::: "memory");                        \
      BAR();                                                                  \
    } }

__global__ __launch_bounds__(512, 2) void gemm_kernel(
    const __hip_bfloat16* __restrict__ A, const __hip_bfloat16* __restrict__ Bm,
    float* __restrict__ rowsum, float* __restrict__ diag)
{
  __shared__ __align__(16) char As[2][32768];   // [2 dbuf][256 rows][64 cols] bf16
  __shared__ __align__(16) char Bs[2][32768];

  const int tid  = threadIdx.x;
  const int lane = tid & 63;
  const int w    = tid >> 6;            // 0..7
  const int wm   = w >> 2, wn = w & 3;  // 2 x 4 wave grid
  const int bm = blockIdx.y, bn = blockIdx.x;
  const long row0 = (long)bm * BM, col0 = (long)bn * BM;
  const char* Abase = (const char*)A;
  const char* Bbase = (const char*)Bm;

  // Stage addressing: thread writes LDS linearly at chunk*8192 + tid*16;
  // swizzle s(L) = L ^ ((row&7)<<4) -> fetch global from logical L = s(p).
  const int srow  = tid >> 3;                                   // 0..63 in chunk
  const int scolb = ((tid & 7) ^ ((tid >> 3) & 7)) << 4;        // swizzled col byte

  // Read addressing (swizzled): row&7 == lane&7 for all fragments.
  const int dsw = (lane & 7) << 4;
  const int rA2 = (((wm * 128 + (lane & 15)) * 128) + ((lane >> 4) * 16)) ^ dsw;
  const int rB2 = (((wn * 64  + (lane & 15)) * 128) + ((lane >> 4) * 16)) ^ dsw;

  f32x4 acc[8][4] = {};
  bf16x8 af[4][2], bfr[4][2];

  // Prologue: stage tile 0 fully + tile 1's first pair; counted wait.
  #pragma unroll
  for (int c = 0; c < 4; c++) STAGE_A(0, 0, c);
  #pragma unroll
  for (int c = 0; c < 4; c++) STAGE_B(0, 0, c);
  STAGE_A(1, 1, 0); STAGE_A(1, 1, 1);
  asm volatile("s_waitcnt vmcnt(2)" ::: "memory");
  BAR();

  #pragma unroll 1
  for (int T = 0; T < NT; T += 2) {
    KTILE(0, T);
    KTILE(1, T + 1);
  }

  // Epilogue: sim = acc*20; diag capture; p = exp(sim); per-row reduce.
  const bool isdiag = (bm == bn);
  const int g = lane >> 4;            // C/D: row=(lane>>4)*4+r, col=lane&15
  #pragma unroll
  for (int m = 0; m < 8; m++) {
    const int rowb = (int)row0 + wm * 128 + m * 16 + g * 4;
    float p[4] = {0.f, 0.f, 0.f, 0.f};
    #pragma unroll
    for (int n = 0; n < 4; n++) {
      const int colb = (int)col0 + wn * 64 + n * 16 + (lane & 15);
      #pragma unroll
      for (int r = 0; r < 4; r++) {
        float sim = acc[m][n][r] * TEMP_INV;
        if (isdiag && (rowb + r == colb)) diag[rowb + r] = sim;
        p[r] += __expf(sim);
      }
    }
    #pragma unroll
    for (int r = 0; r < 4; r++) {
      float s = p[r];
      s += __shfl_xor(s, 1, 64);
      s += __shfl_xor(s, 2, 64);
      s += __shfl_xor(s, 4, 64);
      s += __shfl_xor(s, 8, 64);
      if ((lane & 15) == 0) atomicAdd(&rowsum[rowb + r], s);
    }
  }
}

// Kernel 3: out = mean(log(rowsum) - diag)
__global__ __launch_bounds__(1024) void finalize_kernel(
    const float* __restrict__ rowsum, const float* __restrict__ diag,
    float* __restrict__ out)
{
  int tid = threadIdx.x;
  float acc = 0.f;
  for (int i = tid; i < B_ROWS; i += 1024)
    acc += logf(rowsum[i]) - diag[i];
  #pragma unroll
  for (int off = 1; off < 64; off <<= 1) acc += __shfl_xor(acc, off, 64);
  __shared__ float wsum[16];
  if ((tid & 63) == 0) wsum[tid >> 6] = acc;
  __syncthreads();
  if (tid == 0) {
    float t = 0.f;
    #pragma unroll
    for (int i = 0; i < 16; i++) t += wsum[i];
    out[0] = t * (1.0f / B_ROWS);
  }
}

extern "C" void kernel_launch(void* const* d_in, const int* in_sizes, int n_in,
                              void* d_out, int out_size, void* d_ws, size_t ws_size,
                              hipStream_t stream)
{
  const float* cls = (const float*)d_in[0];
  const float* hid = (const float*)d_in[1];
  float* out = (float*)d_out;
  char* ws = (char*)d_ws;

  __hip_bfloat16* Abf = (__hip_bfloat16*)ws;                                // 8 MB
  __hip_bfloat16* Bbf = (__hip_bfloat16*)(ws + (size_t)B_ROWS * H_DIM * 2); // 8 MB
  float* rowsum = (float*)(ws + (size_t)B_ROWS * H_DIM * 4);                // 16 KB
  float* diag   = rowsum + B_ROWS;                                          // 16 KB

  hipLaunchKernelGGL(normalize_kernel, dim3(2 * B_ROWS), dim3(256), 0, stream,
                     cls, hid, Abf, Bbf, rowsum);
  hipLaunchKernelGGL(gemm_kernel, dim3(B_ROWS / BM, B_ROWS / BM), dim3(512), 0, stream,
                     Abf, Bbf, rowsum, diag);
  hipLaunchKernelGGL(finalize_kernel, dim3(1), dim3(1024), 0, stream,
                     rowsum, diag, out);
}